// Round 14
// baseline (177.601 us; speedup 1.0000x reference)
//
#include <hip/hip_runtime.h>

// B=16, T=1024, N=1024, D=256, WIN=64
// outputs (flat): R (B,T,2D) = [A@V, Q]   : 8388608 f32
//                 alignments (B,N,T) = A^T: 16777216 f32
//                 max_att (B,T)           : 16384 f32
//
// v19 = v18 (156.3us champion: 2-way d-split PV, nt stores, heterogeneous
// grid) + ONE mechanism: zero pre-barrier stores.
//   Every __syncthreads compiles to s_waitcnt vmcnt(0) + s_barrier, and
//   vmcnt counts STORES. v18's hoisted Q->R nt stores sit ahead of the K
//   staging loads in the VMEM queue of every wave, and nt stores ack from
//   HBM (~900cy), not L2 -> all 4 QK barriers chain behind HBM write acks.
//   ("warm L2" rationale for hoisting died when stores became nt.)
//   Moves:
//   1. Q->R copy -> epilogue, remapped to PV's (wave=qg,dh / lane=jj,d4)
//      decomposition; Q rows are L2/L1-hot from QK's reads -> also
//      deduplicates the Q HBM fetch (v8-family FETCH 33MB ~= 2x Q).
//   2. maxatt results kept in regs (compile-time index, unrolled loop),
//      stored after the post-softmax barrier.
//   3. everything else v18 verbatim.

#define BB 16
#define TT 1024
#define NN 1024
#define DD 256
#define WIN 64
#define TBLK 16          // queries per attn block
#define NT 256           // 4 waves
#define NZ 240           // zero-streaming blocks (16 batches x 15)

#define R_ELEMS   (16u*1024u*512u)        // 8388608
#define ALN_ELEMS (16u*1024u*1024u)       // 16777216

#define LSTR 132         // LDS row stride (dwords); 132%32==4 -> conflict-free b128

typedef float f32x4 __attribute__((ext_vector_type(4)));

__device__ __forceinline__ void nts4(void* p, float4 v) {
    f32x4 nv;
    nv.x = v.x; nv.y = v.y; nv.z = v.z; nv.w = v.w;
    __builtin_nontemporal_store(nv, (f32x4*)p);
}

__global__ __launch_bounds__(NT, 4) void attn_v19(
    const float* __restrict__ Q, const float* __restrict__ K,
    const float* __restrict__ V, const int* __restrict__ prev_in,
    float* __restrict__ out)
{
    __shared__ float ks[WIN * LSTR];        // 33792 B: K half-tile
    __shared__ float p_lds[TBLK][WIN + 4];  // 4352 B : probabilities [t][j]

    float* Rout   = out;
    float* aligns = out + R_ELEMS;
    float* maxatt = out + R_ELEMS + ALN_ELEMS;

    const int tid = threadIdx.x;

    // ================= role 1: zero-streaming blocks =================
    if (blockIdx.x < NZ) {
        const int zb    = blockIdx.x;
        const int b     = zb / 15;          // 15 blocks per batch
        const int chunk = zb % 15;          // 64 rows each
        const int prev  = prev_in[b];
        float* zbase = aligns + (size_t)b * NN * TT;
        const float4 z = make_float4(0.f, 0.f, 0.f, 0.f);
        #pragma unroll 8
        for (int r = 0; r < 64; ++r) {
            int idx = chunk * 64 + r;          // 0..959 among non-window rows
            int n   = idx < prev ? idx : idx + WIN;
            nts4(zbase + (size_t)n * 1024 + tid * 4, z);  // nt stream
        }
        return;                                // stores drain under attn compute
    }

    // ================= role 2: attention blocks =================
    const int aid  = blockIdx.x - NZ;
    const int lane = tid & 63;
    const int w    = __builtin_amdgcn_readfirstlane(tid >> 6);  // wave 0..3
    const int b    = aid >> 6;              // 64 blocks per batch
    const int t0   = (aid & 63) * TBLK;
    const int prev = prev_in[b];

    const float* qb = Q + ((size_t)b * TT + t0 + 4 * w) * DD;   // wave-uniform base

    // ================= QK^T over two 128-d halves =================
    // (no stores issued before any barrier: drains wait only on loads)
    float acc[4] = {0.f, 0.f, 0.f, 0.f};
    #pragma unroll
    for (int h = 0; h < 2; ++h) {
        if (h) __syncthreads();             // h0 readers done before restage
        const float4* Ksrc = (const float4*)(K + ((size_t)b * NN + prev) * DD + h * 128);
        #pragma unroll
        for (int k = 0; k < 8; ++k) {
            int t4 = tid + k * NT;          // 0..2047 float4 chunks
            int r = t4 >> 5, c = t4 & 31;
            float4 v = Ksrc[(size_t)r * 64 + c];
            *(float4*)&ks[r * LSTR + c * 4] = v;
        }
        __syncthreads();

        const float* qh = qb + h * 128;
        #pragma unroll 8
        for (int d4 = 0; d4 < 32; ++d4) {
            float4 kk = *(const float4*)&ks[lane * LSTR + d4 * 4];  // conflict-free b128
            #pragma unroll
            for (int t = 0; t < 4; ++t) {
                float4 q = ((const float4*)(qh + t * DD))[d4];      // wave-uniform
                acc[t] = fmaf(q.x, kk.x, fmaf(q.y, kk.y, fmaf(q.z, kk.z, fmaf(q.w, kk.w, acc[t]))));
            }
        }
    }

    // ===== softmax + argmax (wave-local), p -> LDS; maxatt kept in regs =====
    float ma[4];
    #pragma unroll
    for (int t = 0; t < 4; ++t) {
        float v = acc[t] * 0.0625f;         // 1/sqrt(256)

        float m = v;
        #pragma unroll
        for (int off = 32; off; off >>= 1) m = fmaxf(m, __shfl_xor(m, off));

        float e = expf(v - m);
        float s = e;
        #pragma unroll
        for (int off = 32; off; off >>= 1) s += __shfl_xor(s, off);

        p_lds[4 * w + t][lane] = e / s;

        float av = v; int ai = lane;
        #pragma unroll
        for (int off = 32; off; off >>= 1) {
            float ov = __shfl_xor(av, off);
            int   oi = __shfl_xor(ai, off);
            if (ov > av || (ov == av && oi < ai)) { av = ov; ai = oi; }
        }
        ma[t] = (float)(prev + ai);         // store AFTER the barrier
    }
    __syncthreads();                        // all 16 p rows visible (strip + PV)

    // ---- deferred maxatt stores (post-barrier: drain only at endpgm) ----
    if (lane == 0) {
        #pragma unroll
        for (int t = 0; t < 4; ++t)
            __builtin_nontemporal_store(ma[t], &maxatt[(size_t)b * TT + t0 + 4 * w + t]);
    }

    // ===== window-row alignment strip: 64 rows x 16 floats (64B lines) ====
    {
        const int j = tid >> 2, cg = tid & 3;
        float4 v;
        v.x = p_lds[cg * 4 + 0][j];
        v.y = p_lds[cg * 4 + 1][j];
        v.z = p_lds[cg * 4 + 2][j];
        v.w = p_lds[cg * 4 + 3][j];
        nts4(aligns + ((size_t)b * NN + prev + j) * TT + t0 + cg * 4, v);
    }

    // ============== PV: 2-way d-split (V read 2x per block, no spill) =======
    // wave w: queries qg..qg+7, dims [dh*128, dh*128+128).
    // lane = jj*32 + d4: jj = row-half (0..1), d4 = float4 chunk (0..31).
    const int qg = (w >> 1) * 8;            // 0 or 8
    const int dh = w & 1;                   // 0 or 1
    const int jj = lane >> 5;               // 0..1
    const int d4 = lane & 31;               // 0..31
    {
        const float* Vq = V + ((size_t)b * NN + prev + jj * 32) * DD + dh * 128 + d4 * 4;

        float4 o[8];
        #pragma unroll
        for (int t = 0; t < 8; ++t) o[t] = make_float4(0.f, 0.f, 0.f, 0.f);

        #pragma unroll
        for (int k4 = 0; k4 < 8; ++k4) {    // 32 rows per jj-half, 4 at a time
            float4 vv0 = *(const float4*)(Vq + (size_t)(k4 * 4 + 0) * DD);
            float4 vv1 = *(const float4*)(Vq + (size_t)(k4 * 4 + 1) * DD);
            float4 vv2 = *(const float4*)(Vq + (size_t)(k4 * 4 + 2) * DD);
            float4 vv3 = *(const float4*)(Vq + (size_t)(k4 * 4 + 3) * DD);
            #pragma unroll
            for (int t = 0; t < 8; ++t) {
                // 2 addresses across the wave (jj) -> 2-way broadcast, free
                float4 p4 = *(const float4*)&p_lds[qg + t][jj * 32 + k4 * 4];
                o[t].x = fmaf(p4.x, vv0.x, fmaf(p4.y, vv1.x, fmaf(p4.z, vv2.x, fmaf(p4.w, vv3.x, o[t].x))));
                o[t].y = fmaf(p4.x, vv0.y, fmaf(p4.y, vv1.y, fmaf(p4.z, vv2.y, fmaf(p4.w, vv3.y, o[t].y))));
                o[t].z = fmaf(p4.x, vv0.z, fmaf(p4.y, vv1.z, fmaf(p4.z, vv2.z, fmaf(p4.w, vv3.z, o[t].z))));
                o[t].w = fmaf(p4.x, vv0.w, fmaf(p4.y, vv1.w, fmaf(p4.z, vv2.w, fmaf(p4.w, vv3.w, o[t].w))));
            }
        }

        // reduce the two row-halves (lane ^ 32)
        #pragma unroll
        for (int t = 0; t < 8; ++t) {
            o[t].x += __shfl_xor(o[t].x, 32);
            o[t].y += __shfl_xor(o[t].y, 32);
            o[t].z += __shfl_xor(o[t].z, 32);
            o[t].w += __shfl_xor(o[t].w, 32);
        }

        // store: jj group stores rows qg + jj*4 + tt; acc index compile-time,
        // jj-select via cndmask. Two contiguous 512B segments per store.
        #pragma unroll
        for (int tt = 0; tt < 4; ++tt) {
            float4 ov;
            ov.x = jj ? o[tt + 4].x : o[tt].x;
            ov.y = jj ? o[tt + 4].y : o[tt].y;
            ov.z = jj ? o[tt + 4].z : o[tt].z;
            ov.w = jj ? o[tt + 4].w : o[tt].w;
            float* Rp = Rout + ((size_t)b * TT + t0 + qg + jj * 4 + tt) * (2 * DD)
                        + dh * 128 + d4 * 4;
            nts4(Rp, ov);
        }
    }

    // ---- Q->R copy, epilogue (PV mapping; Q rows L2/L1-hot from QK reads) ----
    {
        #pragma unroll
        for (int tt = 0; tt < 4; ++tt) {
            const int row = t0 + qg + jj * 4 + tt;
            float4 qv = *(const float4*)(Q + ((size_t)b * TT + row) * DD + dh * 128 + d4 * 4);
            float* Rp = Rout + ((size_t)b * TT + row) * (2 * DD) + DD + dh * 128 + d4 * 4;
            nts4(Rp, qv);
        }
    }
}

extern "C" void kernel_launch(void* const* d_in, const int* in_sizes, int n_in,
                              void* d_out, int out_size, void* d_ws, size_t ws_size,
                              hipStream_t stream) {
    const float* Q = (const float*)d_in[0];
    const float* K = (const float*)d_in[1];
    const float* V = (const float*)d_in[2];
    const int* prev = (const int*)d_in[3];
    float* out = (float*)d_out;

    // single launch: 240 zero-streaming blocks first, then 1024 attn blocks
    attn_v19<<<NZ + BB * TT / TBLK, NT, 0, stream>>>(Q, K, V, prev, out);
}

// Round 15
// 169.158 us; speedup vs baseline: 1.0499x; 1.0499x over previous
//
#include <hip/hip_runtime.h>

// B=16, T=1024, N=1024, D=256, WIN=64
// outputs (flat): R (B,T,2D) = [A@V, Q]   : 8388608 f32
//                 alignments (B,N,T) = A^T: 16777216 f32
//                 max_att (B,T)           : 16384 f32
//
// v20 = v18 (156.3us champion) + ONE lever: one-generation grid.
//   v18's grid = 1264 blocks > 1024 resident slots (4/CU): the 240 zero-role
//   blocks occupy slots first, pushing 240 attn blocks into a SECOND
//   generation -> span ~= block_dur + block_dur ~= 35us vs ~21us traffic
//   floor. v19's regression proved the prologue Q copy must stay (warms
//   L1/L2 for QK's scalar Q stream).
//   Fix: exactly 1024 attn blocks; each zeroes its 15 non-window rows at
//   the VERY END (after PV's last V-load consumption and the R stores):
//   - in-order vmcnt retirement can't put the store-acks on any load's
//     critical path (v8's mistake was zeros BEFORE PV);
//   - no barrier and no waitcnt after them: stores drain async past
//     s_endpgm, overlapped with other blocks' compute; dispatch-end flush
//     absorbs only the last ~60KB.
//   Everything else v18 verbatim.

#define BB 16
#define TT 1024
#define NN 1024
#define DD 256
#define WIN 64
#define TBLK 16          // queries per attn block
#define NT 256           // 4 waves

#define R_ELEMS   (16u*1024u*512u)        // 8388608
#define ALN_ELEMS (16u*1024u*1024u)       // 16777216

#define LSTR 132         // LDS row stride (dwords); 132%32==4 -> conflict-free b128

typedef float f32x4 __attribute__((ext_vector_type(4)));

__device__ __forceinline__ void nts4(void* p, float4 v) {
    f32x4 nv;
    nv.x = v.x; nv.y = v.y; nv.z = v.z; nv.w = v.w;
    __builtin_nontemporal_store(nv, (f32x4*)p);
}

__global__ __launch_bounds__(NT, 4) void attn_v20(
    const float* __restrict__ Q, const float* __restrict__ K,
    const float* __restrict__ V, const int* __restrict__ prev_in,
    float* __restrict__ out)
{
    __shared__ float ks[WIN * LSTR];        // 33792 B: K half-tile
    __shared__ float p_lds[TBLK][WIN + 4];  // 4352 B : probabilities [t][j]

    float* Rout   = out;
    float* aligns = out + R_ELEMS;
    float* maxatt = out + R_ELEMS + ALN_ELEMS;

    const int tid  = threadIdx.x;
    const int lane = tid & 63;
    const int w    = __builtin_amdgcn_readfirstlane(tid >> 6);  // wave 0..3
    const int b    = blockIdx.x >> 6;       // 64 blocks per batch
    const int t0   = (blockIdx.x & 63) * TBLK;
    const int prev = prev_in[b];

    const float* qb = Q + ((size_t)b * TT + t0 + 4 * w) * DD;   // wave-uniform base

    // ---- hoisted Q copy (nt store; loads warm L1/L2 for QK's scalar stream,
    //      drain overlaps QK compute — v19 proved this must stay) ----
    #pragma unroll
    for (int t = 0; t < 4; ++t) {
        float4 qv = ((const float4*)(qb + t * DD))[lane];
        float* Rrow = Rout + ((size_t)b * TT + t0 + 4 * w + t) * (2 * DD);
        nts4(Rrow + DD + lane * 4, qv);
    }

    // ================= QK^T over two 128-d halves =================
    float acc[4] = {0.f, 0.f, 0.f, 0.f};
    #pragma unroll
    for (int h = 0; h < 2; ++h) {
        if (h) __syncthreads();             // h0 readers done before restage
        const float4* Ksrc = (const float4*)(K + ((size_t)b * NN + prev) * DD + h * 128);
        #pragma unroll
        for (int k = 0; k < 8; ++k) {
            int t4 = tid + k * NT;          // 0..2047 float4 chunks
            int r = t4 >> 5, c = t4 & 31;
            float4 v = Ksrc[(size_t)r * 64 + c];
            *(float4*)&ks[r * LSTR + c * 4] = v;
        }
        __syncthreads();

        const float* qh = qb + h * 128;
        #pragma unroll 8
        for (int d4 = 0; d4 < 32; ++d4) {
            float4 kk = *(const float4*)&ks[lane * LSTR + d4 * 4];  // conflict-free b128
            #pragma unroll
            for (int t = 0; t < 4; ++t) {
                float4 q = ((const float4*)(qh + t * DD))[d4];      // wave-uniform
                acc[t] = fmaf(q.x, kk.x, fmaf(q.y, kk.y, fmaf(q.z, kk.z, fmaf(q.w, kk.w, acc[t]))));
            }
        }
    }

    // ================= softmax + argmax (wave-local), p -> LDS ===========
    #pragma unroll
    for (int t = 0; t < 4; ++t) {
        float v = acc[t] * 0.0625f;         // 1/sqrt(256)

        float m = v;
        #pragma unroll
        for (int off = 32; off; off >>= 1) m = fmaxf(m, __shfl_xor(m, off));

        float e = expf(v - m);
        float s = e;
        #pragma unroll
        for (int off = 32; off; off >>= 1) s += __shfl_xor(s, off);

        p_lds[4 * w + t][lane] = e / s;

        float av = v; int ai = lane;
        #pragma unroll
        for (int off = 32; off; off >>= 1) {
            float ov = __shfl_xor(av, off);
            int   oi = __shfl_xor(ai, off);
            if (ov > av || (ov == av && oi < ai)) { av = ov; ai = oi; }
        }
        if (lane == 0)
            __builtin_nontemporal_store((float)(prev + ai),
                                        &maxatt[(size_t)b * TT + t0 + 4 * w + t]);
    }
    __syncthreads();                        // all 16 p rows visible (strip + PV)

    // ===== window-row alignment strip: 64 rows x 16 floats (64B lines) ====
    {
        const int j = tid >> 2, cg = tid & 3;
        float4 v;
        v.x = p_lds[cg * 4 + 0][j];
        v.y = p_lds[cg * 4 + 1][j];
        v.z = p_lds[cg * 4 + 2][j];
        v.w = p_lds[cg * 4 + 3][j];
        nts4(aligns + ((size_t)b * NN + prev + j) * TT + t0 + cg * 4, v);
    }

    // ============== PV: 2-way d-split (V read 2x per block, no spill) =======
    // wave w: queries qg..qg+7, dims [dh*128, dh*128+128).
    // lane = jj*32 + d4: jj = row-half (0..1), d4 = float4 chunk (0..31).
    {
        const int qg = (w >> 1) * 8;        // 0 or 8
        const int dh = w & 1;               // 0 or 1
        const int jj = lane >> 5;           // 0..1
        const int d4 = lane & 31;           // 0..31
        const float* Vq = V + ((size_t)b * NN + prev + jj * 32) * DD + dh * 128 + d4 * 4;

        float4 o[8];
        #pragma unroll
        for (int t = 0; t < 8; ++t) o[t] = make_float4(0.f, 0.f, 0.f, 0.f);

        #pragma unroll
        for (int k4 = 0; k4 < 8; ++k4) {    // 32 rows per jj-half, 4 at a time
            float4 vv0 = *(const float4*)(Vq + (size_t)(k4 * 4 + 0) * DD);
            float4 vv1 = *(const float4*)(Vq + (size_t)(k4 * 4 + 1) * DD);
            float4 vv2 = *(const float4*)(Vq + (size_t)(k4 * 4 + 2) * DD);
            float4 vv3 = *(const float4*)(Vq + (size_t)(k4 * 4 + 3) * DD);
            #pragma unroll
            for (int t = 0; t < 8; ++t) {
                // 2 addresses across the wave (jj) -> 2-way broadcast, free
                float4 p4 = *(const float4*)&p_lds[qg + t][jj * 32 + k4 * 4];
                o[t].x = fmaf(p4.x, vv0.x, fmaf(p4.y, vv1.x, fmaf(p4.z, vv2.x, fmaf(p4.w, vv3.x, o[t].x))));
                o[t].y = fmaf(p4.x, vv0.y, fmaf(p4.y, vv1.y, fmaf(p4.z, vv2.y, fmaf(p4.w, vv3.y, o[t].y))));
                o[t].z = fmaf(p4.x, vv0.z, fmaf(p4.y, vv1.z, fmaf(p4.z, vv2.z, fmaf(p4.w, vv3.z, o[t].z))));
                o[t].w = fmaf(p4.x, vv0.w, fmaf(p4.y, vv1.w, fmaf(p4.z, vv2.w, fmaf(p4.w, vv3.w, o[t].w))));
            }
        }

        // reduce the two row-halves (lane ^ 32)
        #pragma unroll
        for (int t = 0; t < 8; ++t) {
            o[t].x += __shfl_xor(o[t].x, 32);
            o[t].y += __shfl_xor(o[t].y, 32);
            o[t].z += __shfl_xor(o[t].z, 32);
            o[t].w += __shfl_xor(o[t].w, 32);
        }

        // store: jj group stores rows qg + jj*4 + tt; acc index compile-time,
        // jj-select via cndmask. Two contiguous 512B segments per store.
        #pragma unroll
        for (int tt = 0; tt < 4; ++tt) {
            float4 ov;
            ov.x = jj ? o[tt + 4].x : o[tt].x;
            ov.y = jj ? o[tt + 4].y : o[tt].y;
            ov.z = jj ? o[tt + 4].z : o[tt].z;
            ov.w = jj ? o[tt + 4].w : o[tt].w;
            float* Rp = Rout + ((size_t)b * TT + t0 + qg + jj * 4 + tt) * (2 * DD)
                        + dh * 128 + d4 * 4;
            nts4(Rp, ov);
        }
    }

    // ===== fused zeroing of this block's 15 non-window rows — KERNEL END =====
    // After all loads are consumed; no barrier/waitcnt follows. Stores drain
    // asynchronously past s_endpgm, overlapped with other blocks' compute.
    {
        const int chunk = blockIdx.x & 63;
        float* zbase = aligns + (size_t)b * NN * TT;
        const float4 z = make_float4(0.f, 0.f, 0.f, 0.f);
        #pragma unroll
        for (int r = 0; r < 15; ++r) {
            int idx = chunk * 15 + r;          // 0..959 among non-window rows
            int n   = idx < prev ? idx : idx + WIN;
            nts4(zbase + (size_t)n * 1024 + tid * 4, z);  // 4KB contiguous per row
        }
    }
}

extern "C" void kernel_launch(void* const* d_in, const int* in_sizes, int n_in,
                              void* d_out, int out_size, void* d_ws, size_t ws_size,
                              hipStream_t stream) {
    const float* Q = (const float*)d_in[0];
    const float* K = (const float*)d_in[1];
    const float* V = (const float*)d_in[2];
    const int* prev = (const int*)d_in[3];
    float* out = (float*)d_out;

    // single launch, exactly 1024 blocks = one resident generation at 4/CU
    attn_v20<<<BB * TT / TBLK, NT, 0, stream>>>(Q, K, V, prev, out);
}